// Round 5
// baseline (2036.250 us; speedup 1.0000x reference)
//
#include <hip/hip_runtime.h>
#include <math.h>

#define BN_EPS 1e-5f

typedef unsigned short u16;
typedef short s16x8 __attribute__((ext_vector_type(8)));   // 8 bf16 in 4 VGPRs (MFMA A/B frag)
typedef float f32x4 __attribute__((ext_vector_type(4)));   // MFMA C/D frag

// fast softplus: hardware v_exp/v_log (abs err ~1e-6, threshold is 0.735)
__device__ __forceinline__ float sp_f(float x){
    return fmaxf(x, 0.0f) + __logf(1.0f + __expf(-fabsf(x)));
}
// fast sigmoid: hardware v_rcp
__device__ __forceinline__ float sig_f(float x){
    return __builtin_amdgcn_rcpf(1.0f + __expf(-x));
}
__device__ __forceinline__ u16 f2bf(float f){            // f32 -> bf16 RNE
    unsigned int u = __float_as_uint(f);
    unsigned int r = (u + 0x7fffu + ((u >> 16) & 1u)) >> 16;
    return (u16)r;
}
__device__ __forceinline__ float bf2f(u16 h){
    return __uint_as_float(((unsigned int)h) << 16);
}

// ---------------- embedding: x[n,d] = sum_k af[n,k] * ew[d,k] ----------------
__global__ __launch_bounds__(256) void k_embed(const float* __restrict__ af,
                                               const float* __restrict__ ew,
                                               float* __restrict__ x){
    __shared__ float ew_s[64*93];
    __shared__ float af_s[16*92];
    const int t = threadIdx.x;
    for (int s = t; s < 64*92; s += 256){ int d = s/92, k = s - d*92; ew_s[d*93+k] = ew[s]; }
    const int n0 = blockIdx.x * 16;
    for (int s = t; s < 16*92; s += 256) af_s[s] = af[(size_t)n0*92 + s];
    __syncthreads();
    const int rl = t >> 6, d = t & 63;
    #pragma unroll
    for (int rep = 0; rep < 4; rep++){
        const int row = rep*4 + rl;
        float acc = 0.0f;
        for (int k = 0; k < 92; k++) acc += af_s[row*92+k] * ew_s[d*93+k];
        x[(size_t)(n0+row)*64 + d] = acc;
    }
}

// ---------------- nbr_fea f32 -> bf16 (once) ----------------
__global__ __launch_bounds__(256) void k_nbr2bf(const float* __restrict__ nbr,
                                                u16* __restrict__ nbrb){
    const int tot4 = 16121856/4;
    for (int i = blockIdx.x*256 + threadIdx.x; i < tot4; i += 2048*256){
        float4 v = *reinterpret_cast<const float4*>(nbr + (size_t)i*4);
        ushort4 o; o.x=f2bf(v.x); o.y=f2bf(v.y); o.z=f2bf(v.z); o.w=f2bf(v.w);
        *reinterpret_cast<ushort4*>(nbrb + (size_t)i*4) = o;
    }
}

// ---- W transpose (169x128 f32) + W3 pack: bf16 [o][64], K zero-padded 41->64,
//      8-elem groups XOR-swizzled by (o&7) so LDS copy is linear & reads are 2-way max ----
__global__ void k_transpose_w(const float* __restrict__ W, float* __restrict__ WT,
                              u16* __restrict__ w3tb){
    const int idx = blockIdx.x*256 + threadIdx.x;
    if (idx < 21632){
        const int fp = idx >> 7, o = idx & 127;
        const float w = W[o*169 + fp];
        WT[idx] = w;
        if (fp >= 128){
            const int k = fp - 128;            // 0..40
            const int g = k >> 3, p = k & 7;
            w3tb[o*64 + ((g ^ (o&7))<<3) + p] = f2bf(w);
        }
    } else if (idx < 24576){
        const int idx2 = idx - 21632;          // zero-pad region k=41..63
        const int o = idx2 / 23, k = 41 + idx2 % 23;
        const int g = k >> 3, p = k & 7;
        w3tb[o*64 + ((g ^ (o&7))<<3) + p] = 0;
    }
}

// ---- per-atom terms (bf16 out) + fused previous-layer update of x ----
__global__ __launch_bounds__(256) void k_a12(const float* __restrict__ x,
                                             const float* __restrict__ WT,
                                             const float* __restrict__ bias,
                                             const u16* __restrict__ summedb,
                                             const float* __restrict__ kab2,
                                             int apply,
                                             u16* __restrict__ A1, u16* __restrict__ A2,
                                             float* __restrict__ xout){
    __shared__ float xs[16*64];
    const int t = threadIdx.x;
    const int n0 = blockIdx.x * 16;
    for (int s = t; s < 16*64; s += 256){
        float xv = x[(size_t)n0*64 + s];
        if (apply){
            const int d = s & 63;
            const float sv = bf2f(summedb[(size_t)n0*64 + s]);
            xv = sp_f(xv + sv*kab2[d] + kab2[64+d]);
            xout[(size_t)n0*64 + s] = xv;
        }
        xs[s] = xv;
    }
    __syncthreads();
    const int o = t & 127, rh = t >> 7;
    float a1[8], a2[8];
    const float b = bias[o];
    #pragma unroll
    for (int r = 0; r < 8; r++){ a1[r] = b; a2[r] = 0.0f; }
    for (int d = 0; d < 64; d++){
        const float w1 = WT[d*128 + o];
        const float w2 = WT[(64+d)*128 + o];
        #pragma unroll
        for (int r = 0; r < 8; r++){
            const float xv = xs[(rh*8+r)*64 + d];
            a1[r] += xv*w1; a2[r] += xv*w2;
        }
    }
    #pragma unroll
    for (int r = 0; r < 8; r++){
        const int n = n0 + rh*8 + r;
        A1[(size_t)n*128 + o] = f2bf(a1[r]);
        A2[(size_t)n*128 + o] = f2bf(a2[r]);
    }
}

// ---- per-edge GEMM via MFMA: z[e,o] = (nbr[e,:41] @ W3[:41,o]) + A1[n(e),o] + A2[g(e),o]
//      block = 128 edges x 128 ch, 4 waves (2x2), K=64 (zero-padded), bf16 in / f32 acc ----
__global__ __launch_bounds__(256, 4) void k_conv(
    const u16* __restrict__ nbrb, const int* __restrict__ nidx,
    const u16* __restrict__ A1, const u16* __restrict__ A2,
    const u16* __restrict__ w3tb, u16* __restrict__ z, float* __restrict__ partials)
{
    __shared__ char smem[35840];                 // ab[128][64] + bb[128][64] -> reused as zb[128][140]
    __shared__ float st[256];                    // [0:128) sum, [128:256) sumsq
    u16* ab = (u16*)smem;                        // nbr tile, group-swizzled
    u16* bb = (u16*)(smem + 16384);              // W3^T tile, group-swizzled
    u16* zb = (u16*)smem;                        // D tile bf16 (after MFMA)
    const int t = threadIdx.x;
    st[t] = 0.0f;
    const int e0 = blockIdx.x * 128;

    // stage B: linear 16KB copy (pre-swizzled in global)
    #pragma unroll
    for (int i = 0; i < 4; i++){
        const int off = (i*256 + t) * 8;
        *reinterpret_cast<float4*>(bb + off) =
            *reinterpret_cast<const float4*>(w3tb + off);
    }
    // zero A tile (covers the K-pad), then scatter-fill k<41 with swizzle
    {
        float4 z4; z4.x = 0.f; z4.y = 0.f; z4.z = 0.f; z4.w = 0.f;
        #pragma unroll
        for (int i = 0; i < 4; i++)
            *reinterpret_cast<float4*>(ab + (i*256 + t)*8) = z4;
    }
    __syncthreads();
    for (int s = t; s < 128*41; s += 256){
        const int e = s / 41, k = s - e*41;
        const int g = k >> 3, p = k & 7;
        ab[e*64 + ((g ^ (e&7))<<3) + p] = nbrb[(size_t)e0*41 + s];
    }
    __syncthreads();

    // MFMA: each wave 64x64 (4x4 tiles of 16x16, K=64 as 2x32)
    const int wid = t >> 6, l = t & 63;
    const int wm = wid >> 1, wn = wid & 1;
    const int lrow = l & 15, lk = l >> 4;        // lk in 0..3
    f32x4 acc[4][4];
    #pragma unroll
    for (int m = 0; m < 4; m++)
        #pragma unroll
        for (int n = 0; n < 4; n++)
            acc[m][n] = (f32x4){0.f, 0.f, 0.f, 0.f};
    #pragma unroll
    for (int kk = 0; kk < 2; kk++){
        const int g = kk*4 + lk;                 // 8-elem K-group 0..7
        s16x8 af[4], bf[4];
        #pragma unroll
        for (int m = 0; m < 4; m++){
            const int r = wm*64 + m*16 + lrow;
            af[m] = *reinterpret_cast<const s16x8*>(ab + r*64 + ((g ^ (r&7))<<3));
        }
        #pragma unroll
        for (int n = 0; n < 4; n++){
            const int c = wn*64 + n*16 + lrow;
            bf[n] = *reinterpret_cast<const s16x8*>(bb + c*64 + ((g ^ (c&7))<<3));
        }
        #pragma unroll
        for (int m = 0; m < 4; m++)
            #pragma unroll
            for (int n = 0; n < 4; n++)
                acc[m][n] = __builtin_amdgcn_mfma_f32_16x16x32_bf16(af[m], bf[n], acc[m][n], 0, 0, 0);
    }
    __syncthreads();                             // all ds_reads of ab/bb done -> safe to reuse as zb

    // D -> LDS as bf16 (row = edge, col = channel); row stride 140 u16 breaks bank aliasing
    #pragma unroll
    for (int m = 0; m < 4; m++){
        #pragma unroll
        for (int n = 0; n < 4; n++){
            const int c = wn*64 + n*16 + lrow;
            #pragma unroll
            for (int r4 = 0; r4 < 4; r4++){
                const int r = wm*64 + m*16 + lk*4 + r4;
                zb[r*140 + c] = f2bf(acc[m][n][r4]);
            }
        }
    }
    __syncthreads();

    // epilogue: per thread one (edge, 64-ch half): add gathered A1/A2, write z, BN1 stats
    {
        const int e = t >> 1, half = t & 1;
        const int ge = e0 + e;
        const int n_atom = ge / 12;
        const int gnb = nidx[ge];
        const u16* a1p = A1 + (size_t)n_atom*128 + half*64;
        const u16* a2p = A2 + (size_t)gnb*128 + half*64;
        u16* zp = z + (size_t)ge*128 + half*64;
        const int cbase = half*64;
        #pragma unroll
        for (int jg = 0; jg < 16; jg++){
            ushort4 zv = *reinterpret_cast<const ushort4*>(zb + e*140 + cbase + jg*4);
            ushort4 b1 = *reinterpret_cast<const ushort4*>(a1p + jg*4);
            ushort4 b2 = *reinterpret_cast<const ushort4*>(a2p + jg*4);
            const float o0 = bf2f(zv.x) + bf2f(b1.x) + bf2f(b2.x);
            const float o1 = bf2f(zv.y) + bf2f(b1.y) + bf2f(b2.y);
            const float o2 = bf2f(zv.z) + bf2f(b1.z) + bf2f(b2.z);
            const float o3 = bf2f(zv.w) + bf2f(b1.w) + bf2f(b2.w);
            ushort4 ov; ov.x = f2bf(o0); ov.y = f2bf(o1); ov.z = f2bf(o2); ov.w = f2bf(o3);
            *reinterpret_cast<ushort4*>(zp + jg*4) = ov;
            const int c = cbase + jg*4;
            atomicAdd(&st[c+0], o0); atomicAdd(&st[128+c+0], o0*o0);
            atomicAdd(&st[c+1], o1); atomicAdd(&st[128+c+1], o1*o1);
            atomicAdd(&st[c+2], o2); atomicAdd(&st[128+c+2], o2*o2);
            atomicAdd(&st[c+3], o3); atomicAdd(&st[128+c+3], o3*o3);
        }
    }
    __syncthreads();
    partials[(size_t)blockIdx.x*256 + t] = st[t];
}

// ---------------- BN stats reduce: one block per channel -> kA/kB ----------------
__global__ __launch_bounds__(256) void k_bn_reduce(const float* __restrict__ partials, int nblk, int C,
        float invcount, const float* __restrict__ g, const float* __restrict__ bt,
        float* __restrict__ kab){
    const int c = blockIdx.x;
    const int t = threadIdx.x;
    float s = 0.0f, q = 0.0f;
    for (int b = t; b < nblk; b += 256){
        s += partials[(size_t)b*2*C + c];
        q += partials[(size_t)b*2*C + C + c];
    }
    __shared__ float ls[256], lq[256];
    ls[t] = s; lq[t] = q; __syncthreads();
    for (int off = 128; off > 0; off >>= 1){
        if (t < off){ ls[t] += ls[t+off]; lq[t] += lq[t+off]; }
        __syncthreads();
    }
    if (t == 0){
        const float mean = ls[0]*invcount;
        const float var  = lq[0]*invcount - mean*mean;
        const float rstd = rsqrtf(var + BN_EPS);
        const float ka = g[c]*rstd;
        kab[c]     = ka;
        kab[C + c] = bt[c] - mean*ka;
    }
}

// ---- gate: BN1 + sigmoid*softplus + sum over m + BN2 partials ----
__global__ __launch_bounds__(256, 6) void k_gate(const u16* __restrict__ z,
        const float* __restrict__ kab, u16* __restrict__ summedb,
        float* __restrict__ partials){
    const int t = threadIdx.x;
    const int a = t >> 4, q = t & 15;            // 16 atoms/block, 16 ch-quads
    const int n = blockIdx.x*16 + a;
    const int d0 = q*4;
    float kaf[4], kbf[4], kac[4], kbc[4];
    #pragma unroll
    for (int j = 0; j < 4; j++){
        const int d = d0 + j;
        kaf[j] = kab[d];      kbf[j] = kab[128 + d];
        kac[j] = kab[64 + d]; kbc[j] = kab[192 + d];
    }
    const u16* zp = z + (size_t)n*1536 + d0;
    float acc[4] = {0,0,0,0};
    #pragma unroll 4
    for (int m = 0; m < 12; m++){
        ushort4 fv = *reinterpret_cast<const ushort4*>(zp + m*128);
        ushort4 cv = *reinterpret_cast<const ushort4*>(zp + m*128 + 64);
        acc[0] += sig_f(bf2f(fv.x)*kaf[0]+kbf[0]) * sp_f(bf2f(cv.x)*kac[0]+kbc[0]);
        acc[1] += sig_f(bf2f(fv.y)*kaf[1]+kbf[1]) * sp_f(bf2f(cv.y)*kac[1]+kbc[1]);
        acc[2] += sig_f(bf2f(fv.z)*kaf[2]+kbf[2]) * sp_f(bf2f(cv.z)*kac[2]+kbc[2]);
        acc[3] += sig_f(bf2f(fv.w)*kaf[3]+kbf[3]) * sp_f(bf2f(cv.w)*kac[3]+kbc[3]);
    }
    ushort4 sv; sv.x = f2bf(acc[0]); sv.y = f2bf(acc[1]); sv.z = f2bf(acc[2]); sv.w = f2bf(acc[3]);
    *reinterpret_cast<ushort4*>(summedb + (size_t)n*64 + d0) = sv;
    // reduce across the 4 atoms within each wave (lane bits 4,5)
    float sq[4];
    #pragma unroll
    for (int j = 0; j < 4; j++) sq[j] = acc[j]*acc[j];
    #pragma unroll
    for (int j = 0; j < 4; j++){
        acc[j] += __shfl_xor(acc[j], 16); acc[j] += __shfl_xor(acc[j], 32);
        sq[j]  += __shfl_xor(sq[j],  16); sq[j]  += __shfl_xor(sq[j],  32);
    }
    __shared__ float st[128];
    if (t < 128) st[t] = 0.0f;
    __syncthreads();
    if ((t & 48) == 0){
        #pragma unroll
        for (int j = 0; j < 4; j++){
            atomicAdd(&st[d0 + j], acc[j]);
            atomicAdd(&st[64 + d0 + j], sq[j]);
        }
    }
    __syncthreads();
    if (t < 128) partials[(size_t)blockIdx.x*128 + t] = st[t];
}

// ---- pooled gather fused with last layer's update ----
__global__ __launch_bounds__(256) void k_gather_upd(const float* __restrict__ x,
        const u16* __restrict__ summedb, const float* __restrict__ kab,
        const int* __restrict__ cidx, float* __restrict__ f){
    const int idx = blockIdx.x*256 + threadIdx.x;
    const int r = idx >> 4, q = idx & 15;
    const int src = cidx[r];
    const int d0 = q*4;
    float4 xv = *reinterpret_cast<const float4*>(x + (size_t)src*64 + d0);
    ushort4 s4 = *reinterpret_cast<const ushort4*>(summedb + (size_t)src*64 + d0);
    float4 o;
    o.x = sp_f(xv.x + bf2f(s4.x)*kab[d0+0] + kab[64+d0+0]);
    o.y = sp_f(xv.y + bf2f(s4.y)*kab[d0+1] + kab[64+d0+1]);
    o.z = sp_f(xv.z + bf2f(s4.z)*kab[d0+2] + kab[64+d0+2]);
    o.w = sp_f(xv.w + bf2f(s4.w)*kab[d0+3] + kab[64+d0+3]);
    *reinterpret_cast<float4*>(f + (size_t)r*64 + d0) = o;
}

// ---------------- bilinear edge decoder + fc1 + log_softmax ----------------
__global__ __launch_bounds__(256) void k_edge(
    const float* __restrict__ f, const float* __restrict__ bilW,
    const float* __restrict__ bilb, const float* __restrict__ fc1W,
    const float* __restrict__ fc1b, float* __restrict__ out)
{
    __shared__ float fs[64*68];
    __shared__ float ws[64*68];
    __shared__ float ts[64*68];
    __shared__ float cb[48];
    const int t = threadIdx.x;
    const int b = blockIdx.x;
    for (int s = t; s < 4096; s += 256){
        int i = s >> 6, d = s & 63;
        fs[i*68 + d] = f[(size_t)b*4096 + s];
    }
    if (t < 6){ cb[t] = bilb[t]; cb[6+t] = fc1b[t]; }
    if (t < 36) cb[12+t] = fc1W[t];
    const int ti = t >> 4, tj = t & 15;
    float acc[6][4][4];
    #pragma unroll
    for (int o = 0; o < 6; o++)
        #pragma unroll
        for (int a = 0; a < 4; a++)
            #pragma unroll
            for (int c = 0; c < 4; c++) acc[o][a][c] = 0.0f;

    #pragma unroll
    for (int o = 0; o < 6; o++){
        __syncthreads();
        for (int s = t; s < 4096; s += 256){
            int d = s >> 6, k = s & 63;
            ws[k*68 + d] = bilW[o*4096 + s];
        }
        __syncthreads();
        float T[4][4];
        #pragma unroll
        for (int a = 0; a < 4; a++)
            #pragma unroll
            for (int c = 0; c < 4; c++) T[a][c] = 0.0f;
        for (int d = 0; d < 64; d += 4){
            float4 fv[4], wv[4];
            #pragma unroll
            for (int a = 0; a < 4; a++) fv[a] = *reinterpret_cast<const float4*>(&fs[(a*16+ti)*68 + d]);
            #pragma unroll
            for (int c = 0; c < 4; c++) wv[c] = *reinterpret_cast<const float4*>(&ws[(c*16+tj)*68 + d]);
            #pragma unroll
            for (int a = 0; a < 4; a++)
                #pragma unroll
                for (int c = 0; c < 4; c++)
                    T[a][c] += fv[a].x*wv[c].x + fv[a].y*wv[c].y + fv[a].z*wv[c].z + fv[a].w*wv[c].w;
        }
        __syncthreads();
        #pragma unroll
        for (int a = 0; a < 4; a++)
            #pragma unroll
            for (int c = 0; c < 4; c++)
                ts[(a*16+ti)*68 + c*16+tj] = T[a][c];
        __syncthreads();
        for (int k = 0; k < 64; k += 4){
            float4 ta[4], fb[4];
            #pragma unroll
            for (int a = 0; a < 4; a++) ta[a] = *reinterpret_cast<const float4*>(&ts[(a*16+ti)*68 + k]);
            #pragma unroll
            for (int c = 0; c < 4; c++) fb[c] = *reinterpret_cast<const float4*>(&fs[(c*16+tj)*68 + k]);
            #pragma unroll
            for (int a = 0; a < 4; a++)
                #pragma unroll
                for (int c = 0; c < 4; c++)
                    acc[o][a][c] += ta[a].x*fb[c].x + ta[a].y*fb[c].y + ta[a].z*fb[c].z + ta[a].w*fb[c].w;
        }
    }
    #pragma unroll
    for (int a = 0; a < 4; a++){
        const int i = a*16 + ti;
        #pragma unroll
        for (int c = 0; c < 4; c++){
            const int j = c*16 + tj;
            float v[6];
            float mx = -1e30f;
            #pragma unroll
            for (int p = 0; p < 6; p++){
                float s = cb[6+p];
                #pragma unroll
                for (int o = 0; o < 6; o++) s += cb[12 + p*6 + o] * (acc[o][a][c] + cb[o]);
                v[p] = s;
                mx = fmaxf(mx, s);
            }
            float se = 0.0f;
            #pragma unroll
            for (int p = 0; p < 6; p++) se += __expf(v[p] - mx);
            const float lse = __logf(se) + mx;
            float* op = out + ((size_t)b*4096 + i*64 + j)*6;
            #pragma unroll
            for (int p = 0; p < 6; p++) op[p] = v[p] - lse;
        }
    }
}

// ---------------- atom decoder (W staged+transposed in LDS) ----------------
__global__ __launch_bounds__(256) void k_atomout(const float* __restrict__ f,
        const float* __restrict__ fcaW, const float* __restrict__ fcab,
        float* __restrict__ out){
    __shared__ float wt[64*93];
    const int t = threadIdx.x;
    for (int s = t; s < 5888; s += 256){ int c = s >> 6, d = s & 63; wt[d*93 + c] = fcaW[s]; }
    __syncthreads();
    const int rl = t >> 5, c32 = t & 31;
    for (int rep = 0; rep < 4; rep++){
        const int r = blockIdx.x*32 + rep*8 + rl;
        float acc0 = fcab[c32], acc1 = fcab[c32+32];
        float acc2 = (c32 < 28) ? fcab[c32+64] : 0.0f;
        const float* fr = f + (size_t)r*64;
        for (int d = 0; d < 64; d++){
            const float fv = fr[d];
            const float* wrow = wt + d*93;
            acc0 += fv*wrow[c32];
            acc1 += fv*wrow[c32+32];
            if (c32 < 28) acc2 += fv*wrow[c32+64];
        }
        float* op = out + (size_t)r*92;
        op[c32] = acc0; op[c32+32] = acc1;
        if (c32 < 28) op[c32+64] = acc2;
    }
}

extern "C" void kernel_launch(void* const* d_in, const int* in_sizes, int n_in,
                              void* d_out, int out_size, void* d_ws, size_t ws_size,
                              hipStream_t stream)
{
    (void)in_sizes; (void)n_in; (void)out_size; (void)ws_size;
    const float* atom_fea = (const float*)d_in[0];
    const float* nbr_fea  = (const float*)d_in[1];
    const int*   nbr_idx  = (const int*)  d_in[2];
    const int*   cry_idx  = (const int*)  d_in[3];
    const float* embed_W  = (const float*)d_in[4];
    const float* conv_W   = (const float*)d_in[5];
    const float* conv_b   = (const float*)d_in[6];
    const float* bn1_g    = (const float*)d_in[7];
    const float* bn1_b    = (const float*)d_in[8];
    const float* bn2_g    = (const float*)d_in[9];
    const float* bn2_b    = (const float*)d_in[10];
    const float* bil_W    = (const float*)d_in[11];
    const float* bil_b    = (const float*)d_in[12];
    const float* fc1_W    = (const float*)d_in[13];
    const float* fc1_b    = (const float*)d_in[14];
    const float* fca_W    = (const float*)d_in[15];
    const float* fca_b    = (const float*)d_in[16];
    float* out = (float*)d_out;

    // workspace layout (byte offsets, all 16B aligned; total 165,551,104 B)
    char* wsb = (char*)d_ws;
    float* x       = (float*)(wsb + 0);           //  8,388,608
    u16*   summedb = (u16*)  (wsb + 8388608);     //  4,194,304
    float* WT      = (float*)(wsb + 12582912);    //     87,040
    u16*   w3tb    = (u16*)  (wsb + 12669952);    //     49,152 (3 layers x 16,384)
    float* kab1    = (float*)(wsb + 12719104);    //      1,024
    float* kab2    = (float*)(wsb + 12720128);    //        512
    float* part1   = (float*)(wsb + 12721152);    //  3,145,728
    u16*   A1      = (u16*)  (wsb + 15866880);    //  8,388,608
    u16*   A2      = (u16*)  (wsb + 24255488);    //  8,388,608
    u16*   nbrb    = (u16*)  (wsb + 32644096);    // 32,243,712
    u16*   z       = (u16*)  (wsb + 64887808);    // 100,663,296
    float* fpool   = (float*)A1;                  // reuse A1 region after conv layers
    float* part2   = part1;                       // part1 consumed before gate writes

    k_embed<<<2048, 256, 0, stream>>>(atom_fea, embed_W, x);
    k_nbr2bf<<<2048, 256, 0, stream>>>(nbr_fea, nbrb);

    for (int L = 0; L < 3; L++){
        k_transpose_w<<<96, 256, 0, stream>>>(conv_W + L*128*169, WT, w3tb + L*8192);
        k_a12<<<2048, 256, 0, stream>>>(x, WT, conv_b + L*128, summedb, kab2,
                                        (L > 0) ? 1 : 0, A1, A2, x);
        k_conv<<<3072, 256, 0, stream>>>(nbrb, nbr_idx, A1, A2, w3tb + L*8192, z, part1);
        k_bn_reduce<<<128, 256, 0, stream>>>(part1, 3072, 128, 1.0f/393216.0f,
                                             bn1_g + L*128, bn1_b + L*128, kab1);
        k_gate<<<2048, 256, 0, stream>>>(z, kab1, summedb, part2);
        k_bn_reduce<<<64, 256, 0, stream>>>(part2, 2048, 64, 1.0f/32768.0f,
                                            bn2_g + L*64, bn2_b + L*64, kab2);
    }

    k_gather_upd<<<2048, 256, 0, stream>>>(x, summedb, kab2, cry_idx, fpool);
    k_edge<<<512, 256, 0, stream>>>(fpool, bil_W, bil_b, fc1_W, fc1_b, out);
    k_atomout<<<1024, 256, 0, stream>>>(fpool, fca_W, fca_b, out + 12582912);
}